// Round 5
// baseline (246.377 us; speedup 1.0000x reference)
//
#include <hip/hip_runtime.h>
#include <math.h>

#define B_   16
#define I_   2048
#define AIN_ 16
#define O_   64
#define J_   2048     // O*A_OUT
#define JP_  1024     // j-pairs (route threads own cols 2t, 2t+1)
#define IPB_ 8        // i's per block
#define NSLAB_ 512    // part slabs: [islab*2 + jhalf][16 b][1024 j]
#define NBLK_ 256     // i-slabs

// bf16 pack/unpack (RNE). Inputs finite -> no NaN handling needed.
__device__ __forceinline__ unsigned bf16rne(float f) {
  unsigned u = __float_as_uint(f);
  return (u + 0x7FFFu + ((u >> 16) & 1u)) >> 16;
}
__device__ __forceinline__ float bf16lo(unsigned p) { return __uint_as_float(p << 16); }
__device__ __forceinline__ float bf16hi(unsigned p) { return __uint_as_float(p & 0xFFFF0000u); }

// -------------------------------------------------------------------------
// votes_kernel: votes[i,b,j] = sum_a x[b,i,a] * W[i,a,j] (bf16), AND the
// pass-0 partial preact (route = 1/64 uniform) in f32 registers -> part.
// 1 j per thread (grid 512 = 256 i-slabs x 2 j-halves, 2 blocks/CU):
// live regs = v[16] + acc[16] + 2 w + xv + addr ~= 48 < the 64-VGPR budget
// the backend pins (rounds 1-3: exceeding it spilled ~1 GB/pass to scratch).
// W is read EXACTLY once across the grid. Eliminates round-4's route<0>
// (a full 134 MB votes re-read just for a uniform-weight sum).
// -------------------------------------------------------------------------
__global__ __launch_bounds__(1024) void votes_kernel(
    const float* __restrict__ x, const float* __restrict__ W,
    ushort* __restrict__ votes, float* __restrict__ part)
{
  __shared__ float x_lds[IPB_ * B_ * AIN_];   // 8 KB, [il][b][a]
  const int tid = threadIdx.x;
  const int islab = blockIdx.x >> 1, jh = blockIdx.x & 1;
  const int i0 = islab * IPB_;

  for (int e = tid; e < IPB_ * B_ * AIN_; e += 1024) {
    int b = e >> 7, il = (e >> 4) & 7, a = e & 15;
    x_lds[il * 256 + b * 16 + a] =
        x[(size_t)b * (I_ * AIN_) + (size_t)(i0 + il) * AIN_ + a];
  }
  __syncthreads();

  const int j = jh * 1024 + tid;
  float acc[16];
  #pragma unroll
  for (int b = 0; b < 16; ++b) acc[b] = 0.f;

  for (int il = 0; il < IPB_; ++il) {
    const int i = i0 + il;
    const float* __restrict__ Wi = W + (size_t)i * (AIN_ * J_) + j;
    const float2* __restrict__ xq = (const float2*)x_lds + il * 128; // [b][a2]

    float v[16];
    #pragma unroll
    for (int b = 0; b < 16; ++b) v[b] = 0.f;

    #pragma unroll
    for (int a2 = 0; a2 < 8; ++a2) {
      float w0 = Wi[(size_t)(2 * a2 + 0) * J_];
      float w1 = Wi[(size_t)(2 * a2 + 1) * J_];
      #pragma unroll
      for (int b = 0; b < 16; ++b) {
        float2 xv = xq[b * 8 + a2];          // LDS broadcast
        v[b] = fmaf(xv.x, w0, v[b]);
        v[b] = fmaf(xv.y, w1, v[b]);
      }
    }

    ushort* __restrict__ vo = votes + (size_t)i * (B_ * J_) + j;
    #pragma unroll
    for (int b = 0; b < 16; ++b) {
      acc[b] += v[b];
      vo[(size_t)b * J_] = (ushort)bf16rne(v[b]);
    }
  }

  // part slab = blockIdx.x, layout [512][16][1024]
  float* __restrict__ po = part + (size_t)blockIdx.x * (B_ * 1024) + tid;
  #pragma unroll
  for (int b = 0; b < 16; ++b) po[(size_t)b * 1024] = acc[b] * (1.0f / 64.0f);
}

// -------------------------------------------------------------------------
// route_kernel<PASS> (PASS = 1,2): one routing iteration over bf16 votes.
//   PASS 1: dist = votes.act0; logits := dist; route = softmax(dist)
//   PASS 2: dist = votes.act1; route = softmax(logits + dist)
// 2 j per thread (votes read as packed bf16x2 dwords). Batch halves of 8
// keep per-half live state ~40 regs (acc f2[8] + av f2[8] + vp[8]).
// -------------------------------------------------------------------------
template<int PASS>
__global__ __launch_bounds__(1024) void route_kernel(
    const unsigned* __restrict__ votes, const float* __restrict__ act_in,
    float* __restrict__ part, float* __restrict__ logits)
{
  __shared__ float d_lds[8 * O_];             // 2 KB, distances (one b-half)
  __shared__ float r_lds[8 * O_];             // 2 KB, route     (one b-half)

  const int tid = threadIdx.x, blk = blockIdx.x, i0 = blk * IPB_;
  const int og = tid >> 4;      // o of this thread's two columns (0..63)
  const int lg = tid & 15;      // lane within the 16-lane o-group
  const float2* __restrict__ actq = (const float2*)act_in;
  // part slab for this thread: s = blk*2 + (tid>>9), float2 col (tid&511)
  float2* __restrict__ po =
      (float2*)part + (size_t)(blk * 2 + (tid >> 9)) * (B_ * 512) + (tid & 511);

  for (int h = 0; h < 2; ++h) {
    float2 acc[8];
    #pragma unroll
    for (int bb = 0; bb < 8; ++bb) acc[bb] = make_float2(0.f, 0.f);

    float2 av[8];
    #pragma unroll
    for (int bb = 0; bb < 8; ++bb)
      av[bb] = actq[(size_t)(h * 8 + bb) * JP_ + tid];

    for (int il = 0; il < IPB_; ++il) {
      const int i = i0 + il;
      const unsigned* __restrict__ vo =
          votes + (size_t)i * (B_ * JP_) + (size_t)(h * 8) * JP_ + tid;
      unsigned vp[8];
      #pragma unroll
      for (int bb = 0; bb < 8; ++bb) vp[bb] = vo[(size_t)bb * JP_];

      // distances[b][o] = sum_a v*act: in-thread pair + 4-step xor over 16
      #pragma unroll
      for (int bb = 0; bb < 8; ++bb) {
        float c = bf16lo(vp[bb]) * av[bb].x + bf16hi(vp[bb]) * av[bb].y;
        c += __shfl_xor(c, 1);  c += __shfl_xor(c, 2);
        c += __shfl_xor(c, 4);  c += __shfl_xor(c, 8);
        if (lg == bb) d_lds[bb * 64 + og] = c;
      }
      __syncthreads();

      // softmax over o (waves 0..7: one wave per bb; lane = o)
      if (tid < 512) {
        const int bb2 = tid >> 6, o2 = tid & 63;
        const int b2  = h * 8 + bb2;
        float ell = d_lds[tid];
        if (PASS == 2) ell += logits[((size_t)b2 * I_ + i) * O_ + o2];
        if (PASS == 1) logits[((size_t)b2 * I_ + i) * O_ + o2] = ell;
        float m = ell;
        m = fmaxf(m, __shfl_xor(m, 32)); m = fmaxf(m, __shfl_xor(m, 16));
        m = fmaxf(m, __shfl_xor(m, 8));  m = fmaxf(m, __shfl_xor(m, 4));
        m = fmaxf(m, __shfl_xor(m, 2));  m = fmaxf(m, __shfl_xor(m, 1));
        float e = __expf(ell - m);
        float s = e;
        s += __shfl_xor(s, 32); s += __shfl_xor(s, 16); s += __shfl_xor(s, 8);
        s += __shfl_xor(s, 4);  s += __shfl_xor(s, 2);  s += __shfl_xor(s, 1);
        r_lds[tid] = e / s;
      }
      __syncthreads();

      #pragma unroll
      for (int bb = 0; bb < 8; ++bb) {
        float r = r_lds[bb * 64 + og];
        acc[bb].x = fmaf(r, bf16lo(vp[bb]), acc[bb].x);
        acc[bb].y = fmaf(r, bf16hi(vp[bb]), acc[bb].y);
      }
    }

    #pragma unroll
    for (int bb = 0; bb < 8; ++bb)
      po[(size_t)(h * 8 + bb) * 512] = acc[bb];
  }
}

// -------------------------------------------------------------------------
// reduce_squash: preact[b][j] = sum over 256 i-slabs of part; p += bias;
// squash over a (32-wide). part layout [512 = islab*2+jh][16 b][1024 jloc].
// One wave per (b,o); lanes 0-31 / 32-63 split the 256 slab-partials.
// -------------------------------------------------------------------------
__global__ __launch_bounds__(256) void reduce_squash(
    const float* __restrict__ part, const float* __restrict__ bias,
    float* __restrict__ out)
{
  const int wave = (blockIdx.x * 256 + threadIdx.x) >> 6;   // b*64 + o
  const int L = threadIdx.x & 63;
  const int a = L & 31, q = L >> 5;
  const int b = wave >> 6, o = wave & 63;
  const int jh = o >> 5;
  const int jloc = (o * 32 + a) & 1023;
  const float* __restrict__ base =
      part + (size_t)jh * (B_ * 1024) + (size_t)b * 1024 + jloc;

  float s0 = 0.f, s1 = 0.f;
  #pragma unroll 4
  for (int k = 0; k < 128; k += 2) {
    s0 += base[(size_t)(q * 128 + k)     * (B_ * J_)];
    s1 += base[(size_t)(q * 128 + k + 1) * (B_ * J_)];
  }
  float s = s0 + s1;
  s += __shfl_xor(s, 32);              // combine the two 128-slab halves

  float p = s + bias[o * 32 + a];
  float ns = p * p;
  ns += __shfl_xor(ns, 1);  ns += __shfl_xor(ns, 2);
  ns += __shfl_xor(ns, 4);  ns += __shfl_xor(ns, 8);
  ns += __shfl_xor(ns, 16);
  float scale = sqrtf(ns) / (1.0f + ns);
  if (L < 32) out[wave * 32 + a] = p * scale;
}

// -------------------------------------------------------------------------
// FALLBACK (ws too small): W-streaming pass kernel (round-3 style), writing
// part in the NEW 512-slab layout so the same reduce_squash applies.
// -------------------------------------------------------------------------
template<int PASS>
__global__ __launch_bounds__(1024) void fb_pass_kernel(
    const float* __restrict__ x, const float* __restrict__ W,
    const float* __restrict__ act_in, float* __restrict__ part,
    float* __restrict__ logits)
{
  __shared__ float x_lds[IPB_ * B_ * AIN_];
  __shared__ float d_lds[8 * O_];
  __shared__ float r_lds[8 * O_];
  const int tid = threadIdx.x, blk = blockIdx.x, i0 = blk * IPB_;
  for (int e = tid; e < IPB_ * B_ * AIN_; e += 1024) {
    int b = e >> 7, il = (e >> 4) & 7, a = e & 15;
    x_lds[il * 256 + b * 16 + a] =
        x[(size_t)b * (I_ * AIN_) + (size_t)(i0 + il) * AIN_ + a];
  }
  __syncthreads();
  const int og = tid >> 4, lg = tid & 15;
  float2 acc[16];
  #pragma unroll
  for (int b = 0; b < 16; ++b) acc[b] = make_float2(0.f, 0.f);
  const float2* __restrict__ Wq   = (const float2*)W;
  const float2* __restrict__ actq = (const float2*)act_in;
  for (int il = 0; il < IPB_; ++il) {
    const int i = i0 + il;
    const float2* __restrict__ Wi = Wq + (size_t)i * (AIN_ * JP_);
    const float4* __restrict__ xq = (const float4*)x_lds + il * 64;
    for (int h = 0; h < 2; ++h) {
      float2 v[8];
      #pragma unroll
      for (int bb = 0; bb < 8; ++bb) v[bb] = make_float2(0.f, 0.f);
      #pragma unroll
      for (int a4 = 0; a4 < 4; ++a4) {
        float2 w0 = Wi[(size_t)(a4 * 4 + 0) * JP_ + tid];
        float2 w1 = Wi[(size_t)(a4 * 4 + 1) * JP_ + tid];
        float2 w2 = Wi[(size_t)(a4 * 4 + 2) * JP_ + tid];
        float2 w3 = Wi[(size_t)(a4 * 4 + 3) * JP_ + tid];
        #pragma unroll
        for (int bb = 0; bb < 8; ++bb) {
          float4 xv = xq[(h * 8 + bb) * 4 + a4];
          v[bb].x = fmaf(xv.x, w0.x, v[bb].x); v[bb].y = fmaf(xv.x, w0.y, v[bb].y);
          v[bb].x = fmaf(xv.y, w1.x, v[bb].x); v[bb].y = fmaf(xv.y, w1.y, v[bb].y);
          v[bb].x = fmaf(xv.z, w2.x, v[bb].x); v[bb].y = fmaf(xv.z, w2.y, v[bb].y);
          v[bb].x = fmaf(xv.w, w3.x, v[bb].x); v[bb].y = fmaf(xv.w, w3.y, v[bb].y);
        }
      }
      if (PASS == 0) {
        #pragma unroll
        for (int bb = 0; bb < 8; ++bb) {
          acc[h * 8 + bb].x += v[bb].x; acc[h * 8 + bb].y += v[bb].y;
        }
      } else {
        #pragma unroll
        for (int bb = 0; bb < 8; ++bb) {
          const int b = h * 8 + bb;
          float2 avv = actq[(size_t)b * JP_ + tid];
          float c = v[bb].x * avv.x + v[bb].y * avv.y;
          c += __shfl_xor(c, 1); c += __shfl_xor(c, 2);
          c += __shfl_xor(c, 4); c += __shfl_xor(c, 8);
          if (lg == bb) d_lds[bb * 64 + og] = c;
        }
        __syncthreads();
        if (tid < 512) {
          const int bb2 = tid >> 6, o2 = tid & 63;
          const int b2  = h * 8 + bb2;
          float ell = d_lds[tid];
          if (PASS == 2) ell += logits[((size_t)b2 * I_ + i) * O_ + o2];
          if (PASS == 1) logits[((size_t)b2 * I_ + i) * O_ + o2] = ell;
          float m = ell;
          m = fmaxf(m, __shfl_xor(m, 32)); m = fmaxf(m, __shfl_xor(m, 16));
          m = fmaxf(m, __shfl_xor(m, 8));  m = fmaxf(m, __shfl_xor(m, 4));
          m = fmaxf(m, __shfl_xor(m, 2));  m = fmaxf(m, __shfl_xor(m, 1));
          float e = __expf(ell - m);
          float s = e;
          s += __shfl_xor(s, 32); s += __shfl_xor(s, 16); s += __shfl_xor(s, 8);
          s += __shfl_xor(s, 4);  s += __shfl_xor(s, 2);  s += __shfl_xor(s, 1);
          r_lds[tid] = e / s;
        }
        __syncthreads();
        #pragma unroll
        for (int bb = 0; bb < 8; ++bb) {
          float r = r_lds[bb * 64 + og];
          acc[h * 8 + bb].x = fmaf(r, v[bb].x, acc[h * 8 + bb].x);
          acc[h * 8 + bb].y = fmaf(r, v[bb].y, acc[h * 8 + bb].y);
        }
      }
    }
  }
  const float sc = (PASS == 0) ? (1.0f / 64.0f) : 1.0f;
  float2* __restrict__ po =
      (float2*)part + (size_t)(blk * 2 + (tid >> 9)) * (B_ * 512) + (tid & 511);
  #pragma unroll
  for (int b = 0; b < 16; ++b)
    po[(size_t)b * 512] = make_float2(acc[b].x * sc, acc[b].y * sc);
}

// -------------------------------------------------------------------------
extern "C" void kernel_launch(void* const* d_in, const int* in_sizes, int n_in,
                              void* d_out, int out_size, void* d_ws, size_t ws_size,
                              hipStream_t stream) {
  const float* x    = (const float*)d_in[0];
  const float* W    = (const float*)d_in[1];
  const float* bias = (const float*)d_in[2];
  float* out = (float*)d_out;

  float*  part   = (float*)d_ws;                        // 512*16*1024 f32 = 32 MB
  float*  act    = part + (size_t)NSLAB_ * (B_ * 1024); // 128 KB
  float*  logits = act + (B_ * J_);                     // 8 MB
  ushort* votes  = (ushort*)(logits + (size_t)B_ * I_ * O_);  // 134 MB
  const size_t need = ((size_t)NSLAB_ * B_ * 1024 + B_ * J_ + (size_t)B_ * I_ * O_) * 4
                    + (size_t)I_ * B_ * J_ * 2;

  if (ws_size >= need) {
    votes_kernel<<<NSLAB_, 1024, 0, stream>>>(x, W, votes, part);
    reduce_squash<<<256, 256, 0, stream>>>(part, bias, act);
    route_kernel<1><<<NBLK_, 1024, 0, stream>>>((const unsigned*)votes, act, part, logits);
    reduce_squash<<<256, 256, 0, stream>>>(part, bias, act);
    route_kernel<2><<<NBLK_, 1024, 0, stream>>>((const unsigned*)votes, act, part, logits);
    reduce_squash<<<256, 256, 0, stream>>>(part, bias, out);
  } else {
    fb_pass_kernel<0><<<NBLK_, 1024, 0, stream>>>(x, W, act, part, logits);
    reduce_squash<<<256, 256, 0, stream>>>(part, bias, act);
    fb_pass_kernel<1><<<NBLK_, 1024, 0, stream>>>(x, W, act, part, logits);
    reduce_squash<<<256, 256, 0, stream>>>(part, bias, act);
    fb_pass_kernel<2><<<NBLK_, 1024, 0, stream>>>(x, W, act, part, logits);
    reduce_squash<<<256, 256, 0, stream>>>(part, bias, out);
  }
}

// Round 6
// 233.786 us; speedup vs baseline: 1.0539x; 1.0539x over previous
//
#include <hip/hip_runtime.h>
#include <math.h>

#define B_   16
#define I_   2048
#define AIN_ 16
#define O_   64
#define J_   2048     // O*A_OUT
#define JP_  1024     // j-pairs (thread owns cols 2t, 2t+1)
#define IPB_ 8        // i's per block
#define NSLAB_ 512    // part slabs: [islab*2 + jhalf][16 b][1024 j] (route passes)
#define NBLK_ 256     // i-slabs

// bf16 pack/unpack (RNE). Inputs finite -> no NaN handling needed.
__device__ __forceinline__ unsigned bf16rne(float f) {
  unsigned u = __float_as_uint(f);
  return (u + 0x7FFFu + ((u >> 16) & 1u)) >> 16;
}
__device__ __forceinline__ float bf16lo(unsigned p) { return __uint_as_float(p << 16); }
__device__ __forceinline__ float bf16hi(unsigned p) { return __uint_as_float(p & 0xFFFF0000u); }
__device__ __forceinline__ float bf16us(ushort u) { return __uint_as_float((unsigned)u << 16); }

// non-temporal float2 load (W is a read-once 268 MB stream; keep it out of
// L3 so the 134 MB votes working set stays resident for the route passes)
__device__ __forceinline__ float2 ntload2(const float2* p) {
  union { double d; float2 f; } u;
  u.d = __builtin_nontemporal_load((const double*)p);
  return u.f;
}

// -------------------------------------------------------------------------
// votes_kernel: votes[i,b,j] = sum_a x[b,i,a] * W[i,a,j], stored packed
// bf16x2 dwords at votes[i*16*1024 + b*1024 + jp]. W read EXACTLY once,
// non-temporal. 2 j per thread: live regs = v[16]f2(32) + 2 w f2(4) + xv(2)
// + addr ~8 => ~46 < the 64-VGPR budget the backend pins (rounds 1-3:
// exceeding it spilled ~1 GB/pass). Round-5's 1-j variant (acc folded in)
// degraded stores to 2B/lane and W loads to 4B/lane -> reverted.
// -------------------------------------------------------------------------
__global__ __launch_bounds__(1024) void votes_kernel(
    const float* __restrict__ x, const float* __restrict__ W,
    unsigned* __restrict__ votes)
{
  __shared__ float x_lds[IPB_ * B_ * AIN_];   // 8 KB, [il][b][a]
  const int tid = threadIdx.x, blk = blockIdx.x, i0 = blk * IPB_;

  for (int e = tid; e < IPB_ * B_ * AIN_; e += 1024) {
    int b = e >> 7, il = (e >> 4) & 7, a = e & 15;
    x_lds[il * 256 + b * 16 + a] =
        x[(size_t)b * (I_ * AIN_) + (size_t)(i0 + il) * AIN_ + a];
  }
  __syncthreads();

  const float2* __restrict__ Wq = (const float2*)W;
  for (int il = 0; il < IPB_; ++il) {
    const int i = i0 + il;
    const float2* __restrict__ Wi = Wq + (size_t)i * (AIN_ * JP_);
    const float2* __restrict__ xq = (const float2*)x_lds + il * 128; // [b][a2]

    float2 v[16];
    #pragma unroll
    for (int b = 0; b < 16; ++b) v[b] = make_float2(0.f, 0.f);

    #pragma unroll
    for (int a2 = 0; a2 < 8; ++a2) {        // pairs of a: low w-liveness
      float2 w0 = ntload2(Wi + (size_t)(2 * a2 + 0) * JP_ + tid);
      float2 w1 = ntload2(Wi + (size_t)(2 * a2 + 1) * JP_ + tid);
      #pragma unroll
      for (int b = 0; b < 16; ++b) {
        float2 xv = xq[b * 8 + a2];          // LDS broadcast
        v[b].x = fmaf(xv.x, w0.x, v[b].x);
        v[b].y = fmaf(xv.x, w0.y, v[b].y);
        v[b].x = fmaf(xv.y, w1.x, v[b].x);
        v[b].y = fmaf(xv.y, w1.y, v[b].y);
      }
    }

    unsigned* __restrict__ vo = votes + (size_t)i * (B_ * JP_) + tid;
    #pragma unroll
    for (int b = 0; b < 16; ++b)
      vo[(size_t)b * JP_] = bf16rne(v[b].x) | (bf16rne(v[b].y) << 16);
  }
}

// -------------------------------------------------------------------------
// reduce0_kernel: act0[b,j] = squash( (1/64) * sum_i votes[i,b,j] + bias ).
// Replaces round-4's route<0> (134 MB votes re-read) AND its 64 MB part
// round-trip: reads votes straight out of L3 (just written), writes 128 KB.
// Grid 512 = b*32 + jtile(64 j); block 256 = 64 j x 4 i-subsets; each
// thread sums 512 i's (i = is + 4k) -> LDS reduce -> wave squash.
// -------------------------------------------------------------------------
__global__ __launch_bounds__(256) void reduce0_kernel(
    const ushort* __restrict__ votes, const float* __restrict__ bias,
    float* __restrict__ act)
{
  __shared__ float red[4][64];
  const int b = blockIdx.x >> 5, jt = blockIdx.x & 31;
  const int jl = threadIdx.x & 63, is = threadIdx.x >> 6;
  const int j = jt * 64 + jl;
  const ushort* __restrict__ vp = votes + (size_t)b * J_ + j;

  float s0 = 0.f, s1 = 0.f;
  #pragma unroll 4
  for (int k = 0; k < 512; k += 2) {
    s0 += bf16us(vp[(size_t)(is + 4 * k)     * (B_ * J_)]);
    s1 += bf16us(vp[(size_t)(is + 4 * k + 4) * (B_ * J_)]);
  }
  red[is][jl] = s0 + s1;
  __syncthreads();

  if (threadIdx.x < 64) {
    float p = (red[0][jl] + red[1][jl] + red[2][jl] + red[3][jl]) * (1.0f / 64.0f)
            + bias[j];
    float ns = p * p;                         // squash over a = 32-lane group
    ns += __shfl_xor(ns, 1);  ns += __shfl_xor(ns, 2);
    ns += __shfl_xor(ns, 4);  ns += __shfl_xor(ns, 8);
    ns += __shfl_xor(ns, 16);
    act[(size_t)b * J_ + j] = p * sqrtf(ns) / (1.0f + ns);
  }
}

// -------------------------------------------------------------------------
// route_kernel<PASS> (PASS = 1,2): one routing iteration over bf16 votes.
//   PASS 1: dist = votes.act0; logits := dist; route = softmax(dist)
//   PASS 2: dist = votes.act1; route = softmax(logits + dist)
// 2 j per thread (votes read as packed bf16x2 dwords). Batch halves of 8
// keep per-half live state ~40 regs (acc f2[8] + av f2[8] + vp[8]).
// -------------------------------------------------------------------------
template<int PASS>
__global__ __launch_bounds__(1024) void route_kernel(
    const unsigned* __restrict__ votes, const float* __restrict__ act_in,
    float* __restrict__ part, float* __restrict__ logits)
{
  __shared__ float d_lds[8 * O_];             // 2 KB, distances (one b-half)
  __shared__ float r_lds[8 * O_];             // 2 KB, route     (one b-half)

  const int tid = threadIdx.x, blk = blockIdx.x, i0 = blk * IPB_;
  const int og = tid >> 4;      // o of this thread's two columns (0..63)
  const int lg = tid & 15;      // lane within the 16-lane o-group
  const float2* __restrict__ actq = (const float2*)act_in;
  // part slab for this thread: s = blk*2 + (tid>>9), float2 col (tid&511)
  float2* __restrict__ po =
      (float2*)part + (size_t)(blk * 2 + (tid >> 9)) * (B_ * 512) + (tid & 511);

  for (int h = 0; h < 2; ++h) {
    float2 acc[8];
    #pragma unroll
    for (int bb = 0; bb < 8; ++bb) acc[bb] = make_float2(0.f, 0.f);

    float2 av[8];
    #pragma unroll
    for (int bb = 0; bb < 8; ++bb)
      av[bb] = actq[(size_t)(h * 8 + bb) * JP_ + tid];

    for (int il = 0; il < IPB_; ++il) {
      const int i = i0 + il;
      const unsigned* __restrict__ vo =
          votes + (size_t)i * (B_ * JP_) + (size_t)(h * 8) * JP_ + tid;
      unsigned vp[8];
      #pragma unroll
      for (int bb = 0; bb < 8; ++bb) vp[bb] = vo[(size_t)bb * JP_];

      // distances[b][o] = sum_a v*act: in-thread pair + 4-step xor over 16
      #pragma unroll
      for (int bb = 0; bb < 8; ++bb) {
        float c = bf16lo(vp[bb]) * av[bb].x + bf16hi(vp[bb]) * av[bb].y;
        c += __shfl_xor(c, 1);  c += __shfl_xor(c, 2);
        c += __shfl_xor(c, 4);  c += __shfl_xor(c, 8);
        if (lg == bb) d_lds[bb * 64 + og] = c;
      }
      __syncthreads();

      // softmax over o (waves 0..7: one wave per bb; lane = o)
      if (tid < 512) {
        const int bb2 = tid >> 6, o2 = tid & 63;
        const int b2  = h * 8 + bb2;
        float ell = d_lds[tid];
        if (PASS == 2) ell += logits[((size_t)b2 * I_ + i) * O_ + o2];
        if (PASS == 1) logits[((size_t)b2 * I_ + i) * O_ + o2] = ell;
        float m = ell;
        m = fmaxf(m, __shfl_xor(m, 32)); m = fmaxf(m, __shfl_xor(m, 16));
        m = fmaxf(m, __shfl_xor(m, 8));  m = fmaxf(m, __shfl_xor(m, 4));
        m = fmaxf(m, __shfl_xor(m, 2));  m = fmaxf(m, __shfl_xor(m, 1));
        float e = __expf(ell - m);
        float s = e;
        s += __shfl_xor(s, 32); s += __shfl_xor(s, 16); s += __shfl_xor(s, 8);
        s += __shfl_xor(s, 4);  s += __shfl_xor(s, 2);  s += __shfl_xor(s, 1);
        r_lds[tid] = e / s;
      }
      __syncthreads();

      #pragma unroll
      for (int bb = 0; bb < 8; ++bb) {
        float r = r_lds[bb * 64 + og];
        acc[bb].x = fmaf(r, bf16lo(vp[bb]), acc[bb].x);
        acc[bb].y = fmaf(r, bf16hi(vp[bb]), acc[bb].y);
      }
    }

    #pragma unroll
    for (int bb = 0; bb < 8; ++bb)
      po[(size_t)(h * 8 + bb) * 512] = acc[bb];
  }
}

// -------------------------------------------------------------------------
// reduce_squash: preact[b][j] = sum over 512 slabs of part; p += bias;
// squash over a (32-wide). part layout [512 = islab*2+jh][16 b][1024 jloc].
// One wave per (b,o); lanes 0-31 / 32-63 split the 256 slab-partials.
// -------------------------------------------------------------------------
__global__ __launch_bounds__(256) void reduce_squash(
    const float* __restrict__ part, const float* __restrict__ bias,
    float* __restrict__ out)
{
  const int wave = (blockIdx.x * 256 + threadIdx.x) >> 6;   // b*64 + o
  const int L = threadIdx.x & 63;
  const int a = L & 31, q = L >> 5;
  const int b = wave >> 6, o = wave & 63;
  const int jh = o >> 5;
  const int jloc = (o * 32 + a) & 1023;
  const float* __restrict__ base =
      part + (size_t)jh * (B_ * 1024) + (size_t)b * 1024 + jloc;

  float s0 = 0.f, s1 = 0.f;
  #pragma unroll 4
  for (int k = 0; k < 128; k += 2) {
    s0 += base[(size_t)(q * 128 + k)     * (B_ * J_)];
    s1 += base[(size_t)(q * 128 + k + 1) * (B_ * J_)];
  }
  float s = s0 + s1;
  s += __shfl_xor(s, 32);              // combine the two 128-slab halves

  float p = s + bias[o * 32 + a];
  float ns = p * p;
  ns += __shfl_xor(ns, 1);  ns += __shfl_xor(ns, 2);
  ns += __shfl_xor(ns, 4);  ns += __shfl_xor(ns, 8);
  ns += __shfl_xor(ns, 16);
  float scale = sqrtf(ns) / (1.0f + ns);
  if (L < 32) out[wave * 32 + a] = p * scale;
}

// -------------------------------------------------------------------------
// FALLBACK (ws too small): W-streaming pass kernel, part in 512-slab layout.
// -------------------------------------------------------------------------
template<int PASS>
__global__ __launch_bounds__(1024) void fb_pass_kernel(
    const float* __restrict__ x, const float* __restrict__ W,
    const float* __restrict__ act_in, float* __restrict__ part,
    float* __restrict__ logits)
{
  __shared__ float x_lds[IPB_ * B_ * AIN_];
  __shared__ float d_lds[8 * O_];
  __shared__ float r_lds[8 * O_];
  const int tid = threadIdx.x, blk = blockIdx.x, i0 = blk * IPB_;
  for (int e = tid; e < IPB_ * B_ * AIN_; e += 1024) {
    int b = e >> 7, il = (e >> 4) & 7, a = e & 15;
    x_lds[il * 256 + b * 16 + a] =
        x[(size_t)b * (I_ * AIN_) + (size_t)(i0 + il) * AIN_ + a];
  }
  __syncthreads();
  const int og = tid >> 4, lg = tid & 15;
  float2 acc[16];
  #pragma unroll
  for (int b = 0; b < 16; ++b) acc[b] = make_float2(0.f, 0.f);
  const float2* __restrict__ Wq   = (const float2*)W;
  const float2* __restrict__ actq = (const float2*)act_in;
  for (int il = 0; il < IPB_; ++il) {
    const int i = i0 + il;
    const float2* __restrict__ Wi = Wq + (size_t)i * (AIN_ * JP_);
    const float4* __restrict__ xq = (const float4*)x_lds + il * 64;
    for (int h = 0; h < 2; ++h) {
      float2 v[8];
      #pragma unroll
      for (int bb = 0; bb < 8; ++bb) v[bb] = make_float2(0.f, 0.f);
      #pragma unroll
      for (int a4 = 0; a4 < 4; ++a4) {
        float2 w0 = Wi[(size_t)(a4 * 4 + 0) * JP_ + tid];
        float2 w1 = Wi[(size_t)(a4 * 4 + 1) * JP_ + tid];
        float2 w2 = Wi[(size_t)(a4 * 4 + 2) * JP_ + tid];
        float2 w3 = Wi[(size_t)(a4 * 4 + 3) * JP_ + tid];
        #pragma unroll
        for (int bb = 0; bb < 8; ++bb) {
          float4 xv = xq[(h * 8 + bb) * 4 + a4];
          v[bb].x = fmaf(xv.x, w0.x, v[bb].x); v[bb].y = fmaf(xv.x, w0.y, v[bb].y);
          v[bb].x = fmaf(xv.y, w1.x, v[bb].x); v[bb].y = fmaf(xv.y, w1.y, v[bb].y);
          v[bb].x = fmaf(xv.z, w2.x, v[bb].x); v[bb].y = fmaf(xv.z, w2.y, v[bb].y);
          v[bb].x = fmaf(xv.w, w3.x, v[bb].x); v[bb].y = fmaf(xv.w, w3.y, v[bb].y);
        }
      }
      if (PASS == 0) {
        #pragma unroll
        for (int bb = 0; bb < 8; ++bb) {
          acc[h * 8 + bb].x += v[bb].x; acc[h * 8 + bb].y += v[bb].y;
        }
      } else {
        #pragma unroll
        for (int bb = 0; bb < 8; ++bb) {
          const int b = h * 8 + bb;
          float2 avv = actq[(size_t)b * JP_ + tid];
          float c = v[bb].x * avv.x + v[bb].y * avv.y;
          c += __shfl_xor(c, 1); c += __shfl_xor(c, 2);
          c += __shfl_xor(c, 4); c += __shfl_xor(c, 8);
          if (lg == bb) d_lds[bb * 64 + og] = c;
        }
        __syncthreads();
        if (tid < 512) {
          const int bb2 = tid >> 6, o2 = tid & 63;
          const int b2  = h * 8 + bb2;
          float ell = d_lds[tid];
          if (PASS == 2) ell += logits[((size_t)b2 * I_ + i) * O_ + o2];
          if (PASS == 1) logits[((size_t)b2 * I_ + i) * O_ + o2] = ell;
          float m = ell;
          m = fmaxf(m, __shfl_xor(m, 32)); m = fmaxf(m, __shfl_xor(m, 16));
          m = fmaxf(m, __shfl_xor(m, 8));  m = fmaxf(m, __shfl_xor(m, 4));
          m = fmaxf(m, __shfl_xor(m, 2));  m = fmaxf(m, __shfl_xor(m, 1));
          float e = __expf(ell - m);
          float s = e;
          s += __shfl_xor(s, 32); s += __shfl_xor(s, 16); s += __shfl_xor(s, 8);
          s += __shfl_xor(s, 4);  s += __shfl_xor(s, 2);  s += __shfl_xor(s, 1);
          r_lds[tid] = e / s;
        }
        __syncthreads();
        #pragma unroll
        for (int bb = 0; bb < 8; ++bb) {
          float r = r_lds[bb * 64 + og];
          acc[h * 8 + bb].x = fmaf(r, v[bb].x, acc[h * 8 + bb].x);
          acc[h * 8 + bb].y = fmaf(r, v[bb].y, acc[h * 8 + bb].y);
        }
      }
    }
  }
  const float sc = (PASS == 0) ? (1.0f / 64.0f) : 1.0f;
  float2* __restrict__ po =
      (float2*)part + (size_t)(blk * 2 + (tid >> 9)) * (B_ * 512) + (tid & 511);
  #pragma unroll
  for (int b = 0; b < 16; ++b)
    po[(size_t)b * 512] = make_float2(acc[b].x * sc, acc[b].y * sc);
}

// -------------------------------------------------------------------------
extern "C" void kernel_launch(void* const* d_in, const int* in_sizes, int n_in,
                              void* d_out, int out_size, void* d_ws, size_t ws_size,
                              hipStream_t stream) {
  const float* x    = (const float*)d_in[0];
  const float* W    = (const float*)d_in[1];
  const float* bias = (const float*)d_in[2];
  float* out = (float*)d_out;

  float*    part   = (float*)d_ws;                        // 32 MB
  float*    act    = part + (size_t)NSLAB_ * (B_ * 1024); // 128 KB
  float*    logits = act + (B_ * J_);                     // 8 MB
  unsigned* votes  = (unsigned*)(logits + (size_t)B_ * I_ * O_);  // 134 MB
  const size_t need = ((size_t)NSLAB_ * B_ * 1024 + B_ * J_ + (size_t)B_ * I_ * O_) * 4
                    + (size_t)I_ * B_ * JP_ * 4;

  if (ws_size >= need) {
    votes_kernel<<<NBLK_, 1024, 0, stream>>>(x, W, votes);
    reduce0_kernel<<<512, 256, 0, stream>>>((const ushort*)votes, bias, act);
    route_kernel<1><<<NBLK_, 1024, 0, stream>>>(votes, act, part, logits);
    reduce_squash<<<256, 256, 0, stream>>>(part, bias, act);
    route_kernel<2><<<NBLK_, 1024, 0, stream>>>(votes, act, part, logits);
    reduce_squash<<<256, 256, 0, stream>>>(part, bias, out);
  } else {
    fb_pass_kernel<0><<<NBLK_, 1024, 0, stream>>>(x, W, act, part, logits);
    reduce_squash<<<256, 256, 0, stream>>>(part, bias, act);
    fb_pass_kernel<1><<<NBLK_, 1024, 0, stream>>>(x, W, act, part, logits);
    reduce_squash<<<256, 256, 0, stream>>>(part, bias, act);
    fb_pass_kernel<2><<<NBLK_, 1024, 0, stream>>>(x, W, act, part, logits);
    reduce_squash<<<256, 256, 0, stream>>>(part, bias, out);
  }
}